// Round 6
// baseline (83.816 us; speedup 1.0000x reference)
//
#include <hip/hip_runtime.h>

typedef __attribute__((ext_vector_type(8))) short short8;
typedef __attribute__((ext_vector_type(4))) float f32x4;
typedef __attribute__((ext_vector_type(4))) unsigned short u16x4;

#define DI __device__ __forceinline__

namespace {
constexpr int TOT_ = 512;                 // output row width (floats)
constexpr int XROW = 2048;                // x row width (floats) = F*D
constexpr int RPB  = 512;                 // rows per block (4 waves x 128)
constexpr int NB_  = (16384 / RPB) * 64;  // 2048 blocks
}

DI unsigned short f2bf(float v) {
    __bf16 h = (__bf16)v;                 // RNE convert
    return __builtin_bit_cast(unsigned short, h);
}

__global__ __launch_bounds__(256, 6)
void recon_kernel(const float* __restrict__ x, const float* __restrict__ W1,
                  const float* __restrict__ b1, const float* __restrict__ W2,
                  const float* __restrict__ b2, float* __restrict__ out)
{
    __shared__ __align__(16) unsigned short w1t[64 * 32];    // [n<64][k<32]
    __shared__ __align__(16) unsigned short w2t[32 * 64];    // [n<32][k<64]
    __shared__ __align__(16) unsigned short hb[4][16 * 64];  // per-wave h^T tile

    // XCD-aware remap: per XCD, all 64 features of four 512-row groups are
    // co-resident -> x slabs and out lines shared within one L2.
    const int bid = blockIdx.x;                 // 0..2047
    const int xcd = bid & 7;
    const int ii  = bid >> 3;                   // 0..255
    const int f   = ii & 63;
    const int rg  = (xcd << 2) | (ii >> 6);     // 0..31

    const int tid  = threadIdx.x;
    const int lane = tid & 63;
    const int wv   = tid >> 6;
    const int l15  = lane & 15;
    const int kg   = lane >> 4;
    const int swz  = (l15 & 7) << 3;            // XOR swizzle (16-B granule)
    const bool catf = (f < 32);                 // categorical (card>1)?

    const int r0 = rg * RPB + wv * 128;         // wave's 128 rows (8 m-tiles)
    const float* xb = x + (size_t)(r0 + l15) * XROW + f * 32 + kg * 8;

    // ---- prime 2-slot rolling x buffer (tiles 0,1); latency hides under
    //      the weight staging + barrier below ----
    f32x4 xs[2][2];
#pragma unroll
    for (int s = 0; s < 2; ++s) {
        const float* p = xb + (size_t)(s * 16) * XROW;
        xs[s][0] = *(const f32x4*)p;
        xs[s][1] = *(const f32x4*)(p + 4);
    }

    // ---- stage W1^T (always) and W2^T (card>1 only) as bf16 ----
    const float* W1f = W1 + f * 2048;
    const float* W2f = W2 + f * 2048;
    {
        const int e0 = tid * 8;                 // 256 thr x 8 = 2048 elements
        f32x4 v0 = *(const f32x4*)(W1f + e0);
        f32x4 v1 = *(const f32x4*)(W1f + e0 + 4);
        if (catf) {
            f32x4 u0 = *(const f32x4*)(W2f + e0);
            f32x4 u1 = *(const f32x4*)(W2f + e0 + 4);
#pragma unroll
            for (int j = 0; j < 8; ++j) {
                int e = e0 + j;
                float u = (j < 4) ? u0[j] : u1[j - 4];
                w2t[(e & 31) * 64 + (e >> 5)] = f2bf(u);   // W2: e = k*32 + n
            }
        }
#pragma unroll
        for (int j = 0; j < 8; ++j) {
            int e = e0 + j;
            float v = (j < 4) ? v0[j] : v1[j - 4];
            w1t[(e & 63) * 32 + (e >> 6)] = f2bf(v);       // W1: e = k*64 + n
        }
    }
    __syncthreads();

    // ---- fragments (swapped-operand layout) ----
    short8 w1b[4];                               // W1[k][c]: c=l15, k=kg*8+j
#pragma unroll
    for (int nt = 0; nt < 4; ++nt)
        w1b[nt] = *(const short8*)&w1t[(nt * 16 + l15) * 32 + kg * 8];

    short8 w2b[2][2] = {};                       // W2[k][c]: c=l15, k=ks*32+kg*8+j
    if (catf) {
#pragma unroll
        for (int nt = 0; nt < 2; ++nt)
#pragma unroll
            for (int ks = 0; ks < 2; ++ks)
                w2b[nt][ks] = *(const short8*)&w2t[(nt * 16 + l15) * 64 + ks * 32 + kg * 8];
    } else {
        // card==1: only output column 0 used -> fill all A-rows with W2[k][0]
#pragma unroll
        for (int ks = 0; ks < 2; ++ks)
#pragma unroll
            for (int j = 0; j < 8; ++j)
                w2b[0][ks][j] = (short)f2bf(W2f[(ks * 32 + kg * 8 + j) * 32]);
    }

    // biases along the per-lane column quad (fed as MFMA C-operand)
    f32x4 b1q[4], b2q[2];
#pragma unroll
    for (int nt = 0; nt < 4; ++nt) b1q[nt] = *(const f32x4*)(b1 + f * 64 + nt * 16 + kg * 4);
#pragma unroll
    for (int nt = 0; nt < 2; ++nt) b2q[nt] = *(const f32x4*)(b2 + f * 32 + nt * 16 + kg * 4);

    // output gather params (CARDS = [4,8,16,32]*8 ++ [1]*32)
    int card, off;
    if (catf) { card = 4 << (f & 3); off = (f >> 2) * 60 + card - 4; }
    else      { card = 1;            off = 480 + (f - 32); }

    unsigned short* hw = hb[wv];

#pragma unroll
    for (int t = 0; t < 8; ++t) {
        const int s = t & 1;                     // current slot (compile-time)
        short8 af;                               // x[r=l15][k=kg*8+j]
#pragma unroll
        for (int j = 0; j < 4; ++j) {
            af[j]     = (short)f2bf(xs[s][0][j]);
            af[4 + j] = (short)f2bf(xs[s][1][j]);
        }
        if (t + 2 < 8) {                         // rolling prefetch into slot s
            const float* p = xb + (size_t)((t + 2) * 16) * XROW;
            xs[s][0] = *(const f32x4*)p;
            xs[s][1] = *(const f32x4*)(p + 4);
        }

        // GEMM1 swapped, bias in acc: lane holds h[c=nt*16+kg*4+j][r=l15]
        f32x4 c1[4];
#pragma unroll
        for (int nt = 0; nt < 4; ++nt)
            c1[nt] = __builtin_amdgcn_mfma_f32_16x16x32_bf16(w1b[nt], af, b1q[nt], 0, 0, 0);

        // ReLU -> packed bf16x4 -> one ds_write_b64 per nt (swizzled)
#pragma unroll
        for (int nt = 0; nt < 4; ++nt) {
            u16x4 hv;
#pragma unroll
            for (int j = 0; j < 4; ++j) {
                float v = c1[nt][j];
                hv[j] = f2bf(v > 0.f ? v : 0.f);
            }
            *(u16x4*)&hw[(l15 * 64 + nt * 16 + kg * 4) ^ swz] = hv;
        }

        // GEMM2 A-fragments (h[r=l15][k=ks*32+kg*8+j]) from swizzled LDS
        short8 ha[2];
#pragma unroll
        for (int ks = 0; ks < 2; ++ks)
            ha[ks] = *(const short8*)&hw[(l15 * 64 + ks * 32 + kg * 8) ^ swz];

        // GEMM2 swapped, bias in acc: lane holds out[c=nt*16+kg*4+j][r=l15]
        f32x4 c2[2];
        c2[0] = __builtin_amdgcn_mfma_f32_16x16x32_bf16(w2b[0][0], ha[0], b2q[0], 0, 0, 0);
        c2[0] = __builtin_amdgcn_mfma_f32_16x16x32_bf16(w2b[0][1], ha[1], c2[0], 0, 0, 0);
        if (card == 32) {
            c2[1] = __builtin_amdgcn_mfma_f32_16x16x32_bf16(w2b[1][0], ha[0], b2q[1], 0, 0, 0);
            c2[1] = __builtin_amdgcn_mfma_f32_16x16x32_bf16(w2b[1][1], ha[1], c2[1], 0, 0, 0);
        }

        // store: each active lane writes one aligned dwordx4 (bias already in)
        const int row = r0 + t * 16 + l15;
        if (card > 1) {
            const int ntiles = (card == 32) ? 2 : 1;
            for (int nt = 0; nt < ntiles; ++nt) {
                if (kg * 4 < card - nt * 16) {
                    f32x4 v;
#pragma unroll
                    for (int j = 0; j < 4; ++j) v[j] = c2[nt][j];
                    *(f32x4*)(out + (size_t)row * TOT_ + off + nt * 16 + kg * 4) = v;
                }
            }
        } else {
            if (kg == 0)
                out[(size_t)row * TOT_ + off] = c2[0][0];
        }
    }
}

extern "C" void kernel_launch(void* const* d_in, const int* in_sizes, int n_in,
                              void* d_out, int out_size, void* d_ws, size_t ws_size,
                              hipStream_t stream) {
    const float* x  = (const float*)d_in[0];
    const float* W1 = (const float*)d_in[1];
    const float* b1 = (const float*)d_in[2];
    const float* W2 = (const float*)d_in[3];
    const float* b2 = (const float*)d_in[4];
    float* out = (float*)d_out;
    recon_kernel<<<NB_, 256, 0, stream>>>(x, W1, b1, W2, b2, out);
}

// Round 7
// 79.692 us; speedup vs baseline: 1.0518x; 1.0518x over previous
//
#include <hip/hip_runtime.h>

typedef __attribute__((ext_vector_type(8))) short short8;
typedef __attribute__((ext_vector_type(4))) float f32x4;
typedef __attribute__((ext_vector_type(4))) unsigned short u16x4;
typedef __attribute__((ext_vector_type(8))) unsigned short u16x8;

#define DI __device__ __forceinline__

namespace {
constexpr int TOT_ = 512;            // output row width (floats)
constexpr int XROW = 2048;           // x row width (floats) = F*D
constexpr int RPB  = 32;             // rows per main block
constexpr int NBM  = 16384 / RPB;    // 512 main blocks
}

DI unsigned short f2bf(float v) {
    __bf16 h = (__bf16)v;            // RNE convert
    return __builtin_bit_cast(unsigned short, h);
}

// ---- prep: W1/W2 f32 -> bf16 transposed layouts in d_ws (512 KB) ----
// ws[0..131072)       : W1^T per feature, [f][n<64][k<32]
// ws[131072..262144)  : W2^T per feature, [f][n<32][k<64]
__global__ __launch_bounds__(256)
void prep_kernel(const float* __restrict__ W1, const float* __restrict__ W2,
                 unsigned short* __restrict__ ws)
{
    __shared__ __align__(16) unsigned short w1t[2048];
    __shared__ __align__(16) unsigned short w2t[2048];
    const int f = blockIdx.x, tid = threadIdx.x, e0 = tid * 8;
    const float* W1f = W1 + f * 2048;
    const float* W2f = W2 + f * 2048;
    f32x4 v0 = *(const f32x4*)(W1f + e0), v1 = *(const f32x4*)(W1f + e0 + 4);
    f32x4 u0 = *(const f32x4*)(W2f + e0), u1 = *(const f32x4*)(W2f + e0 + 4);
#pragma unroll
    for (int j = 0; j < 8; ++j) {
        int e = e0 + j;
        w1t[(e & 63) * 32 + (e >> 6)] = f2bf(j < 4 ? v0[j] : v1[j - 4]);  // e=k*64+n
        w2t[(e & 31) * 64 + (e >> 5)] = f2bf(j < 4 ? u0[j] : u1[j - 4]);  // e=k*32+n
    }
    __syncthreads();
    *(short8*)(ws + f * 2048 + e0)          = *(const short8*)(w1t + e0);
    *(short8*)(ws + 131072 + f * 2048 + e0) = *(const short8*)(w2t + e0);
}

// ---- main: block = 32 rows x all 64 features; x staged contiguously ----
__global__ __launch_bounds__(512)
void recon_kernel(const float* __restrict__ x, const unsigned short* __restrict__ ws,
                  const float* __restrict__ b1, const float* __restrict__ b2,
                  float* __restrict__ out)
{
    __shared__ __align__(16) unsigned short slab[32 * 1024];  // 64 KB bf16 x-slab (one phase)
    __shared__ __align__(16) unsigned short hb[8][1024];      // per-wave h^T tiles

    const int r0   = blockIdx.x * RPB;
    const int tid  = threadIdx.x, lane = tid & 63, wv = tid >> 6;  // 8 waves
    const int mt   = wv >> 2;              // m-tile 0/1 (16 rows each)
    const int fg   = wv & 3;               // feature-group within phase
    const int l15  = lane & 15, kg = lane >> 4;
    const int swz  = (l15 & 7) << 3;       // XOR swizzle (16-B granule)
    const unsigned short* ws1 = ws;
    const unsigned short* ws2 = ws + 131072;
    unsigned short* hw = hb[wv];

    const int srow = wv >> 1;              // staging row offset 0..3
    const int su   = (wv & 1) * 64 + lane; // staging unit 0..127 (8 floats each)

    for (int p = 0; p < 2; ++p) {          // phase p: features [p*32, p*32+32)
        if (p) __syncthreads();            // protect slab reuse
        // ---- stage x[32 rows][1024 cols] -> bf16 slab; each wave-instr
        //      reads 2 KB CONTIGUOUS (canonical stream) ----
#pragma unroll
        for (int it = 0; it < 8; ++it) {
            const int row = it * 4 + srow;
            const float* xp = x + (size_t)(r0 + row) * XROW + p * 1024 + su * 8;
            f32x4 a = *(const f32x4*)xp, b = *(const f32x4*)(xp + 4);
            u16x8 hv;
#pragma unroll
            for (int j = 0; j < 4; ++j) { hv[j] = f2bf(a[j]); hv[4 + j] = f2bf(b[j]); }
            *(u16x8*)&slab[(row * 1024 + su * 8) ^ ((row & 7) << 3)] = hv;
        }
        __syncthreads();

        // ---- compute: each wave does 8 features of this phase ----
#pragma unroll 2
        for (int i = 0; i < 8; ++i) {
            const int f = p * 32 + fg * 8 + i;
            // x A-fragment from swizzled slab: row=mt*16+l15, k=flocal*32+kg*8
            short8 af = *(const short8*)
                &slab[((mt * 16 + l15) * 1024 + (fg * 8 + i) * 32 + kg * 8) ^ swz];

            // GEMM1 swapped, bias in acc: lane holds h[c=nt*16+kg*4+j][r=l15]
            const unsigned short* w1f = ws1 + f * 2048;
            f32x4 c1[4];
#pragma unroll
            for (int nt = 0; nt < 4; ++nt) {
                short8 w1b = *(const short8*)&w1f[(nt * 16 + l15) * 32 + kg * 8];
                f32x4 b1q  = *(const f32x4*)(b1 + f * 64 + nt * 16 + kg * 4);
                c1[nt] = __builtin_amdgcn_mfma_f32_16x16x32_bf16(w1b, af, b1q, 0, 0, 0);
            }
            // ReLU -> packed bf16x4 -> wave-private swizzled LDS
#pragma unroll
            for (int nt = 0; nt < 4; ++nt) {
                u16x4 hv;
#pragma unroll
                for (int j = 0; j < 4; ++j) {
                    float v = c1[nt][j];
                    hv[j] = f2bf(v > 0.f ? v : 0.f);
                }
                *(u16x4*)&hw[(l15 * 64 + nt * 16 + kg * 4) ^ swz] = hv;
            }
            short8 ha0 = *(const short8*)&hw[(l15 * 64 + kg * 8) ^ swz];
            short8 ha1 = *(const short8*)&hw[(l15 * 64 + 32 + kg * 8) ^ swz];

            // GEMM2 swapped, bias in acc; store gathered columns
            const unsigned short* w2f = ws2 + f * 2048;
            const int row = r0 + mt * 16 + l15;
            if (p == 0) {                   // categorical: card = 4<<(i&3)
                const int card = 4 << (i & 3);
                const int off  = (f >> 2) * 60 + card - 4;
                f32x4 c2[2];
                {
                    short8 w200 = *(const short8*)&w2f[l15 * 64 + kg * 8];
                    short8 w201 = *(const short8*)&w2f[l15 * 64 + 32 + kg * 8];
                    f32x4 b2q0  = *(const f32x4*)(b2 + f * 32 + kg * 4);
                    c2[0] = __builtin_amdgcn_mfma_f32_16x16x32_bf16(w200, ha0, b2q0, 0, 0, 0);
                    c2[0] = __builtin_amdgcn_mfma_f32_16x16x32_bf16(w201, ha1, c2[0], 0, 0, 0);
                }
                if (card == 32) {
                    short8 w210 = *(const short8*)&w2f[(16 + l15) * 64 + kg * 8];
                    short8 w211 = *(const short8*)&w2f[(16 + l15) * 64 + 32 + kg * 8];
                    f32x4 b2q1  = *(const f32x4*)(b2 + f * 32 + 16 + kg * 4);
                    c2[1] = __builtin_amdgcn_mfma_f32_16x16x32_bf16(w210, ha0, b2q1, 0, 0, 0);
                    c2[1] = __builtin_amdgcn_mfma_f32_16x16x32_bf16(w211, ha1, c2[1], 0, 0, 0);
                }
                const int ntiles = (card == 32) ? 2 : 1;
                for (int nt = 0; nt < ntiles; ++nt) {
                    if (kg * 4 < card - nt * 16) {
                        f32x4 v;
#pragma unroll
                        for (int j = 0; j < 4; ++j) v[j] = c2[nt][j];
                        *(f32x4*)(out + (size_t)row * TOT_ + off + nt * 16 + kg * 4) = v;
                    }
                }
            } else {                        // numerical: card==1, only col 0 of W2
                short8 w20 = *(const short8*)&w2f[kg * 8];        // W2[k][0] = elem k
                short8 w21 = *(const short8*)&w2f[32 + kg * 8];
                f32x4 b2q0 = *(const f32x4*)(b2 + f * 32 + kg * 4);
                f32x4 c2;
                c2 = __builtin_amdgcn_mfma_f32_16x16x32_bf16(w20, ha0, b2q0, 0, 0, 0);
                c2 = __builtin_amdgcn_mfma_f32_16x16x32_bf16(w21, ha1, c2, 0, 0, 0);
                if (kg == 0)
                    out[(size_t)row * TOT_ + 480 + (f - 32)] = c2[0];
            }
        }
    }
}

extern "C" void kernel_launch(void* const* d_in, const int* in_sizes, int n_in,
                              void* d_out, int out_size, void* d_ws, size_t ws_size,
                              hipStream_t stream) {
    const float* x  = (const float*)d_in[0];
    const float* W1 = (const float*)d_in[1];
    const float* b1 = (const float*)d_in[2];
    const float* W2 = (const float*)d_in[3];
    const float* b2 = (const float*)d_in[4];
    float* out = (float*)d_out;
    unsigned short* ws = (unsigned short*)d_ws;   // needs 512 KB
    prep_kernel<<<64, 256, 0, stream>>>(W1, W2, ws);
    recon_kernel<<<NBM, 512, 0, stream>>>(x, ws, b1, b2, out);
}

// Round 8
// 45.122 us; speedup vs baseline: 1.8575x; 1.7661x over previous
//
#include <hip/hip_runtime.h>

typedef __attribute__((ext_vector_type(8))) short short8;
typedef __attribute__((ext_vector_type(4))) float f32x4;
typedef __attribute__((ext_vector_type(4))) unsigned short u16x4;

#define DI __device__ __forceinline__

namespace {
constexpr int TOT_ = 512;                 // output row width (floats)
constexpr int XROW = 2048;                // x row width (floats) = F*D
constexpr int BT_  = 256;                 // batch rows per block
constexpr int NB_  = (16384 / BT_) * 64;  // 4096 blocks
}

DI unsigned short f2bf(float v) {
    __bf16 h = (__bf16)v;                 // RNE convert
    return __builtin_bit_cast(unsigned short, h);
}

// ---- prep: W1/W2 f32 -> bf16 transposed layouts in d_ws (512 KB) ----
// ws[0..131072)       : W1^T per feature, [f][n<64][k<32]
// ws[131072..262144)  : W2^T per feature, [f][n<32][k<64]
// (validated in R6: full pipeline passed with these layouts)
__global__ __launch_bounds__(256)
void prep_kernel(const float* __restrict__ W1, const float* __restrict__ W2,
                 unsigned short* __restrict__ ws)
{
    __shared__ __align__(16) unsigned short w1t[2048];
    __shared__ __align__(16) unsigned short w2t[2048];
    const int f = blockIdx.x, tid = threadIdx.x, e0 = tid * 8;
    const float* W1f = W1 + f * 2048;
    const float* W2f = W2 + f * 2048;
    f32x4 v0 = *(const f32x4*)(W1f + e0), v1 = *(const f32x4*)(W1f + e0 + 4);
    f32x4 u0 = *(const f32x4*)(W2f + e0), u1 = *(const f32x4*)(W2f + e0 + 4);
#pragma unroll
    for (int j = 0; j < 8; ++j) {
        int e = e0 + j;
        w1t[(e & 63) * 32 + (e >> 6)] = f2bf(j < 4 ? v0[j] : v1[j - 4]);  // e=k*64+n
        w2t[(e & 31) * 64 + (e >> 5)] = f2bf(j < 4 ? u0[j] : u1[j - 4]);  // e=k*32+n
    }
    __syncthreads();
    *(short8*)(ws + f * 2048 + e0)          = *(const short8*)(w1t + e0);
    *(short8*)(ws + 131072 + f * 2048 + e0) = *(const short8*)(w2t + e0);
}

// ---- main: barrier-free; weights as coalesced bf16 fragment loads ----
__global__ __launch_bounds__(256)
void recon_kernel(const float* __restrict__ x, const unsigned short* __restrict__ ws,
                  const float* __restrict__ b1, const float* __restrict__ b2,
                  float* __restrict__ out)
{
    __shared__ __align__(16) unsigned short hb[4][16 * 64];  // per-wave h^T tile (8 KB)

    // XCD-aware remap: per XCD, all 64 features of one 256-row region are
    // co-resident -> full 8-KB x rows read together, out lines merge in L2.
    const int bid   = blockIdx.x;               // 0..4095
    const int f     = (bid >> 3) & 63;
    const int btile = ((bid & 7) << 3) | (bid >> 9);

    const int tid  = threadIdx.x;
    const int lane = tid & 63;
    const int wv   = tid >> 6;
    const int l15  = lane & 15;
    const int kg   = lane >> 4;
    const int swz  = (l15 & 7) << 3;            // XOR swizzle (16-B granule)
    const bool catf = (f < 32);                 // categorical (card>1)?

    const unsigned short* ws1 = ws + f * 2048;
    const unsigned short* ws2 = ws + 131072 + f * 2048;

    // ---- weight/bias fragments first (L2-hot, coalesced short8) ----
    short8 w1b[4];                               // W1[k][c]: c=l15, k=kg*8+j
#pragma unroll
    for (int nt = 0; nt < 4; ++nt)
        w1b[nt] = *(const short8*)&ws1[(nt * 16 + l15) * 32 + kg * 8];

    short8 w2b[2][2];                            // W2[k][c]: c=l15, k=ks*32+kg*8+j
    if (catf) {
#pragma unroll
        for (int nt = 0; nt < 2; ++nt)
#pragma unroll
            for (int ks = 0; ks < 2; ++ks)
                w2b[nt][ks] = *(const short8*)&ws2[(nt * 16 + l15) * 64 + ks * 32 + kg * 8];
    } else {
        // card==1: only output column 0 used; W2^T column 0 is contiguous
#pragma unroll
        for (int ks = 0; ks < 2; ++ks)
            w2b[0][ks] = *(const short8*)&ws2[ks * 32 + kg * 8];
        w2b[1][0] = w2b[0][0]; w2b[1][1] = w2b[0][1];
    }

    f32x4 b1q[4], b2q[2];                        // fed as MFMA C-operand
#pragma unroll
    for (int nt = 0; nt < 4; ++nt) b1q[nt] = *(const f32x4*)(b1 + f * 64 + nt * 16 + kg * 4);
#pragma unroll
    for (int nt = 0; nt < 2; ++nt) b2q[nt] = *(const f32x4*)(b2 + f * 32 + nt * 16 + kg * 4);

    // ---- then the HBM x loads (tile t usable at vmcnt fences progressively) ----
    const int b0 = btile * BT_ + wv * 64;
    f32x4 xa[4][2];
#pragma unroll
    for (int t = 0; t < 4; ++t) {
        const float* xr = x + (size_t)(b0 + t * 16 + l15) * XROW + f * 32 + kg * 8;
        xa[t][0] = *(const f32x4*)xr;
        xa[t][1] = *(const f32x4*)(xr + 4);
    }

    // output gather params (CARDS = [4,8,16,32]*8 ++ [1]*32)
    int card, off;
    if (catf) { card = 4 << (f & 3); off = (f >> 2) * 60 + card - 4; }
    else      { card = 1;            off = 480 + (f - 32); }

    unsigned short* hw = hb[wv];

#pragma unroll
    for (int t = 0; t < 4; ++t) {
        short8 af;                               // x[r=l15][k=kg*8+j]
#pragma unroll
        for (int j = 0; j < 4; ++j) {
            af[j]     = (short)f2bf(xa[t][0][j]);
            af[4 + j] = (short)f2bf(xa[t][1][j]);
        }

        // GEMM1 swapped, bias in acc: lane holds h[c=nt*16+kg*4+j][r=l15]
        f32x4 c1[4];
#pragma unroll
        for (int nt = 0; nt < 4; ++nt)
            c1[nt] = __builtin_amdgcn_mfma_f32_16x16x32_bf16(w1b[nt], af, b1q[nt], 0, 0, 0);

        // ReLU -> packed bf16x4 -> wave-private swizzled LDS (no barrier)
#pragma unroll
        for (int nt = 0; nt < 4; ++nt) {
            u16x4 hv;
#pragma unroll
            for (int j = 0; j < 4; ++j) {
                float v = c1[nt][j];
                hv[j] = f2bf(v > 0.f ? v : 0.f);
            }
            *(u16x4*)&hw[(l15 * 64 + nt * 16 + kg * 4) ^ swz] = hv;
        }

        // GEMM2 A-fragments (h[r=l15][k=ks*32+kg*8+j]) from swizzled LDS
        short8 ha[2];
#pragma unroll
        for (int ks = 0; ks < 2; ++ks)
            ha[ks] = *(const short8*)&hw[(l15 * 64 + ks * 32 + kg * 8) ^ swz];

        // GEMM2 swapped, bias in acc: lane holds out[c=nt*16+kg*4+j][r=l15]
        f32x4 c2[2];
        c2[0] = __builtin_amdgcn_mfma_f32_16x16x32_bf16(w2b[0][0], ha[0], b2q[0], 0, 0, 0);
        c2[0] = __builtin_amdgcn_mfma_f32_16x16x32_bf16(w2b[0][1], ha[1], c2[0], 0, 0, 0);
        if (card == 32) {
            c2[1] = __builtin_amdgcn_mfma_f32_16x16x32_bf16(w2b[1][0], ha[0], b2q[1], 0, 0, 0);
            c2[1] = __builtin_amdgcn_mfma_f32_16x16x32_bf16(w2b[1][1], ha[1], c2[1], 0, 0, 0);
        }

        // store: each active lane writes one aligned dwordx4 (bias already in)
        const int row = b0 + t * 16 + l15;
        if (card > 1) {
            const int ntiles = (card == 32) ? 2 : 1;
            for (int nt = 0; nt < ntiles; ++nt) {
                if (kg * 4 < card - nt * 16) {
                    f32x4 v;
#pragma unroll
                    for (int j = 0; j < 4; ++j) v[j] = c2[nt][j];
                    *(f32x4*)(out + (size_t)row * TOT_ + off + nt * 16 + kg * 4) = v;
                }
            }
        } else {
            if (kg == 0)
                out[(size_t)row * TOT_ + off] = c2[0][0];
        }
    }
}

extern "C" void kernel_launch(void* const* d_in, const int* in_sizes, int n_in,
                              void* d_out, int out_size, void* d_ws, size_t ws_size,
                              hipStream_t stream) {
    const float* x  = (const float*)d_in[0];
    const float* W1 = (const float*)d_in[1];
    const float* b1 = (const float*)d_in[2];
    const float* W2 = (const float*)d_in[3];
    const float* b2 = (const float*)d_in[4];
    float* out = (float*)d_out;
    unsigned short* ws = (unsigned short*)d_ws;   // needs 512 KB
    prep_kernel<<<64, 256, 0, stream>>>(W1, W2, ws);
    recon_kernel<<<NB_, 256, 0, stream>>>(x, ws, b1, b2, out);
}